// Round 10
// baseline (34.076 us; speedup 1.0000x reference)
//
#include <hip/hip_runtime.h>
#include <math.h>

#define NPTS 16384
#define DIM  24
#define KPAD 32
#define ESIG 65536
#define ERND 32768
#define THRESH 2.0f
#define LDSS 36      // 72 B LDS row stride: <=2-way banking on b128 ops (free)
#define NBLK 4160    // triangular knn block count: sum_{bi<64}(128-2*bi)

typedef __attribute__((ext_vector_type(8))) short bf16x8;
typedef __attribute__((ext_vector_type(4))) float f32x4;

// ws layout: ushort Ab[16384*32]; ushort Bb[16384*32]

__device__ __forceinline__ unsigned short f2bf(float x) {
    unsigned int u = __float_as_uint(x);
    unsigned int r = u + 0x7fffu + ((u >> 16) & 1u);
    return (unsigned short)(r >> 16);
}

__device__ __forceinline__ float min3f(float a, float b, float c) {
    return fminf(fminf(a, b), c);   // fuses to v_min3_f32
}

__device__ __forceinline__ float wave_reduce(float v) {
#pragma unroll
    for (int off = 32; off > 0; off >>= 1)
        v += __shfl_down(v, off, 64);
    return v;
}

// block sum on thread 0 (256-thread blocks)
__device__ __forceinline__ float block_reduce256(float v) {
    __shared__ float red[4];
    int lane = threadIdx.x & 63;
    int wid  = threadIdx.x >> 6;
    v = wave_reduce(v);
    if (lane == 0) red[wid] = v;
    __syncthreads();
    float s = 0.f;
    if (threadIdx.x == 0) s = red[0] + red[1] + red[2] + red[3];
    return s;
}

__device__ __forceinline__ float edge_d2(const float* __restrict__ emb, int a, int b) {
    const float4* ra = reinterpret_cast<const float4*>(emb + (size_t)a * DIM);
    const float4* rb = reinterpret_cast<const float4*>(emb + (size_t)b * DIM);
    float d2 = 0.f;
#pragma unroll
    for (int k = 0; k < 6; ++k) {
        float4 va = ra[k], vb = rb[k];
        float dx = va.x - vb.x, dy = va.y - vb.y;
        float dz = va.z - vb.z, dw = va.w - vb.w;
        d2 += dx * dx; d2 += dy * dy; d2 += dz * dz; d2 += dw * dw;
    }
    return d2;
}

// blocks [0,64): prep Ab/Bb; [64,192): signal edges (512/block); [192,256): random edges
__global__ __launch_bounds__(256) void fused_pre_kernel(
    const float* __restrict__ emb, const int* __restrict__ sedge,
    const int* __restrict__ redge, const int* __restrict__ pid,
    unsigned short* __restrict__ Ab, unsigned short* __restrict__ Bb,
    float* __restrict__ out)
{
    int b = blockIdx.x, t = threadIdx.x;
    if (b < 64) {
        int i = b * 256 + t;
        const float4* rp = reinterpret_cast<const float4*>(emb + (size_t)i * DIM);
        float v[24];
        float s = 0.f;
#pragma unroll
        for (int k = 0; k < 6; ++k) {
            float4 q = rp[k];
            v[4*k+0] = q.x; v[4*k+1] = q.y; v[4*k+2] = q.z; v[4*k+3] = q.w;
            s += q.x*q.x + q.y*q.y + q.z*q.z + q.w*q.w;
        }
        union { unsigned short u[32]; int4 q[4]; } a, bb;
#pragma unroll
        for (int k = 0; k < 24; ++k) { a.u[k] = f2bf(-2.f * v[k]); bb.u[k] = f2bf(v[k]); }
        a.u[24] = f2bf(s);   a.u[25] = (unsigned short)0x3F80;
        bb.u[24] = (unsigned short)0x3F80; bb.u[25] = f2bf(s);
#pragma unroll
        for (int k = 26; k < 32; ++k) { a.u[k] = 0; bb.u[k] = 0; }
        int4* pa = reinterpret_cast<int4*>(Ab + (size_t)i * KPAD);
        int4* pb = reinterpret_cast<int4*>(Bb + (size_t)i * KPAD);
#pragma unroll
        for (int k = 0; k < 4; ++k) { pa[k] = a.q[k]; pb[k] = bb.q[k]; }
    } else if (b < 192) {
        int eb = b - 64;                 // 128 blocks, 512 edges each, 2/thread
        int e0 = eb * 512 + t, e1 = e0 + 256;
        float d2 = edge_d2(emb, sedge[e0], sedge[ESIG + e0])
                 + edge_d2(emb, sedge[e1], sedge[ESIG + e1]) + 2e-12f;
        float s = block_reduce256(d2);
        if (t == 0) atomicAdd(out, s * (1.f / ESIG));
    } else {
        int eb = b - 192;                // 64 blocks, 512 edges each, 2/thread
        int e0 = eb * 512 + t, e1 = e0 + 256;
        int a0 = redge[e0], b0 = redge[ERND + e0];
        int a1 = redge[e1], b1 = redge[ERND + e1];
        float val = 0.f;
        if (pid[a0] != pid[b0]) {
            float d = sqrtf(edge_d2(emb, a0, b0) + 1e-12f);
            float h = 1.f - d;
            if (h > 0.f) val = h * h;
        }
        if (pid[a1] != pid[b1]) {
            float d = sqrtf(edge_d2(emb, a1, b1) + 1e-12f);
            float h = 1.f - d;
            if (h > 0.f) val += h * h;
        }
        float s = block_reduce256(val);
        if (t == 0) atomicAdd(out, s * (1.f / ERND));
    }
}

// One-shot 256x128 tile per block, compact triangular grid (bj >= 2*bi).
// B-panel staged in LDS once; A fragments direct from global (coalesced 1 KB/instr).
// 8 waves (4x2), each 64x64 = 16 MFMA; min3-fold; rare candidates rechecked
// inline in exact fp32; per-wave atomicAdd (weight 2: i<j only).
__global__ __launch_bounds__(512) void knn_mfma_kernel(
    const unsigned short* __restrict__ Ab, const unsigned short* __restrict__ Bb,
    const float* __restrict__ emb, const int* __restrict__ pid,
    float* __restrict__ out)
{
    // decode compact id -> (bi, bj): C(bi) = bi*(129-bi), bj = 2*bi + (id - C(bi))
    const int id = blockIdx.x;
    int bi = (int)((129.0f - sqrtf(16641.0f - 4.0f * (float)id)) * 0.5f);
    while (bi * (129 - bi) > id) --bi;
    while ((bi + 1) * (129 - (bi + 1)) <= id) ++bi;
    const int bj = 2 * bi + (id - bi * (129 - bi));

    __shared__ short lB[128 * LDSS];
    const int t  = threadIdx.x;
    const int i0 = bi * 256, j0 = bj * 128;

    // stage B panel: 128 rows x 64 B, one int4 per thread (coalesced)
    {
        int row = t >> 2, q = t & 3;
        int4 v = *reinterpret_cast<const int4*>(Bb + (size_t)(j0 + row) * KPAD + q * 8);
        *reinterpret_cast<int4*>(&lB[row * LDSS + q * 8]) = v;
    }

    const int wid = t >> 6, lane = t & 63;
    const int wr = wid >> 1, wc = wid & 1;          // 4x2 wave grid
    const int lrow = lane & 15, lkb = (lane >> 4) * 8;

    // A fragments: direct global, 1 KB contiguous per instruction per wave
    bf16x8 af[4];
#pragma unroll
    for (int r = 0; r < 4; ++r)
        af[r] = *reinterpret_cast<const bf16x8*>(
            Ab + (size_t)(i0 + wr * 64 + r * 16 + lrow) * KPAD + lkb);

    __syncthreads();

    bf16x8 bfr[4];
#pragma unroll
    for (int c = 0; c < 4; ++c)
        bfr[c] = *reinterpret_cast<const bf16x8*>(
            &lB[(wc * 64 + c * 16 + lrow) * LDSS + lkb]);

    const f32x4 zero = {0.f, 0.f, 0.f, 0.f};
    f32x4 acc[4][4];
#pragma unroll
    for (int r = 0; r < 4; ++r)
#pragma unroll
        for (int c = 0; c < 4; ++c)
            acc[r][c] = __builtin_amdgcn_mfma_f32_16x16x32_bf16(af[r], bfr[c], zero, 0, 0, 0);

    // min over the 64 d^2 values this lane holds (min3 trees)
    float tm[16];
#pragma unroll
    for (int r = 0; r < 4; ++r)
#pragma unroll
        for (int c = 0; c < 4; ++c)
            tm[r * 4 + c] = fminf(min3f(acc[r][c][0], acc[r][c][1], acc[r][c][2]),
                                  acc[r][c][3]);
    float m0 = min3f(tm[0], tm[1], tm[2]);
    float m1 = min3f(tm[3], tm[4], tm[5]);
    float m2 = min3f(tm[6], tm[7], tm[8]);
    float m3 = min3f(tm[9], tm[10], tm[11]);
    float m4 = min3f(tm[12], tm[13], tm[14]);
    float mn = fminf(min3f(min3f(m0, m1, m2), m3, m4), tm[15]);

    float lacc = 0.f;
    if (mn < THRESH) {   // fires only for diagonal tiles / true near-pairs
#pragma unroll
        for (int r = 0; r < 4; ++r)
#pragma unroll
            for (int c = 0; c < 4; ++c)
#pragma unroll
                for (int e = 0; e < 4; ++e) {
                    if (acc[r][c][e] < THRESH) {
                        int i = i0 + wr * 64 + r * 16 + (lane >> 4) * 4 + e;
                        int j = j0 + wc * 64 + c * 16 + (lane & 15);
                        if (i < j && pid[i] != pid[j]) {
                            float d = sqrtf(fmaxf(edge_d2(emb, i, j), 0.f) + 1e-12f);
                            if (d < 1.f) { float h = 1.f - d; lacc += h * h; }
                        }
                    }
                }
    }

    if (__any(lacc != 0.f)) {
        float wsum = wave_reduce(lacc);
        if (lane == 0) atomicAdd(out, wsum * (2.f / NPTS));
    }
}

extern "C" void kernel_launch(void* const* d_in, const int* in_sizes, int n_in,
                              void* d_out, int out_size, void* d_ws, size_t ws_size,
                              hipStream_t stream) {
    const float* emb   = (const float*)d_in[0];
    const int*   sedge = (const int*)d_in[1];
    const int*   redge = (const int*)d_in[2];
    const int*   pid   = (const int*)d_in[3];
    float* out = (float*)d_out;

    unsigned short* Ab = (unsigned short*)d_ws;               // 16384*32
    unsigned short* Bb = Ab + (size_t)NPTS * KPAD;            // 16384*32

    hipMemsetAsync(out, 0, sizeof(float), stream);
    fused_pre_kernel<<<256, 256, 0, stream>>>(emb, sedge, redge, pid, Ab, Bb, out);
    knn_mfma_kernel<<<NBLK, 512, 0, stream>>>(Ab, Bb, emb, pid, out);
}